// Round 1
// baseline (999.232 us; speedup 1.0000x reference)
//
#include <hip/hip_runtime.h>
#include <hip/hip_bf16.h>

#define NN 50000
#define NR 8
#define NE 400000
#define DD 256

typedef __attribute__((ext_vector_type(8))) short short8v;
typedef __attribute__((ext_vector_type(4))) float f32x4;

static __device__ __forceinline__ ushort f2b(float f) {
  union { float f; unsigned u; } v; v.f = f;
  unsigned u = v.u;
  unsigned r = (u + 0x7fffu + ((u >> 16) & 1u)) >> 16;
  return (ushort)r;
}

// ---------------- CSR build ----------------

__global__ void k_hist(const int* __restrict__ dst, int* __restrict__ deg) {
  int tid = blockIdx.x * blockDim.x + threadIdx.x;
  int stride = gridDim.x * blockDim.x;
  for (int e = tid; e < NR * NE; e += stride) {
    int r = e / NE;
    atomicAdd(&deg[r * NN + dst[e]], 1);
  }
}

__global__ __launch_bounds__(1024) void k_scan(const int* __restrict__ deg,
                                               int* __restrict__ offs) {
  int r = blockIdx.x;
  int t = threadIdx.x, lane = t & 63, w = t >> 6;  // 16 waves
  __shared__ int wsum[16];
  __shared__ int carry;
  if (t == 0) carry = 0;
  __syncthreads();
  for (int base = 0; base < NN; base += 1024) {
    int v = (base + t < NN) ? deg[r * NN + base + t] : 0;
    int s = v;
    #pragma unroll
    for (int off = 1; off < 64; off <<= 1) {
      int u = __shfl_up(s, off, 64);
      if (lane >= off) s += u;
    }
    if (lane == 63) wsum[w] = s;
    __syncthreads();  // wsum visible
    int wbase = 0, total = 0;
    #pragma unroll
    for (int i = 0; i < 16; ++i) {
      int ws_i = wsum[i];
      wbase += (i < w) ? ws_i : 0;
      total += ws_i;
    }
    int c = carry;
    if (base + t < NN) offs[r * NN + base + t] = c + wbase + (s - v);
    __syncthreads();  // all reads of wsum/carry done
    if (t == 0) carry += total;
    __syncthreads();  // update visible before next chunk
  }
}

__global__ void k_fill(const int* __restrict__ src, const int* __restrict__ dst,
                       const int* __restrict__ offs, int* __restrict__ cur,
                       int* __restrict__ csr) {
  int tid = blockIdx.x * blockDim.x + threadIdx.x;
  int stride = gridDim.x * blockDim.x;
  for (int e = tid; e < NR * NE; e += stride) {
    int r = e / NE;
    int d = dst[e];
    int p = offs[r * NN + d] + atomicAdd(&cur[r * NN + d], 1);
    csr[(size_t)r * NE + p] = src[e];
  }
}

// ---------------- weights -> bf16, transposed [seg][n][k] ----------------

__global__ void k_wconv(const float* __restrict__ w, const float* __restrict__ lw,
                        ushort* __restrict__ wb) {
  int i = blockIdx.x * blockDim.x + threadIdx.x;
  if (i >= 9 * 65536) return;
  int s = i >> 16, rem = i & 65535, k = rem >> 8, n = rem & 255;
  float v = (s < 8) ? w[(size_t)s * 65536 + k * 256 + n] : lw[k * 256 + n];
  wb[(size_t)s * 65536 + (size_t)n * 256 + k] = f2b(v);
}

// ---------------- aggregation: one wave per (node, relation) ----------------
// xa[(r-r0)*strideR + n*256 + c] = bf16( (1/max(deg,1)) * sum_{e in CSR[r,n]} x[src_e][c] )
// relation 8 == self-loop: xa row = bf16(x[n]) (no normalization).

__global__ __launch_bounds__(256) void k_agg(const float* __restrict__ x,
                                             const int* __restrict__ csr,
                                             const int* __restrict__ offs,
                                             const int* __restrict__ deg,
                                             ushort* __restrict__ xa,
                                             long strideR, int r0) {
  int wid = threadIdx.x >> 6, lane = threadIdx.x & 63;
  int n = blockIdx.x * 4 + wid;
  int r = r0 + blockIdx.y;
  if (n >= NN) return;
  float ax = 0.f, ay = 0.f, az = 0.f, aw = 0.f;
  if (r == 8) {
    const float4 v = *(const float4*)(x + (size_t)n * 256 + lane * 4);
    ax = v.x; ay = v.y; az = v.z; aw = v.w;
  } else {
    int base = offs[r * NN + n];
    int dg = deg[r * NN + n];
    const int* lst = csr + (size_t)r * NE + base;
    for (int j = 0; j < dg; ++j) {
      int s = lst[j];
      const float4 v = *(const float4*)(x + (size_t)s * 256 + lane * 4);
      ax += v.x; ay += v.y; az += v.z; aw += v.w;
    }
    float inv = 1.f / (float)max(dg, 1);
    ax *= inv; ay *= inv; az *= inv; aw *= inv;
  }
  ushort4 o;
  o.x = f2b(ax); o.y = f2b(ay); o.z = f2b(az); o.w = f2b(aw);
  *(ushort4*)(xa + (size_t)(r - r0) * strideR + (size_t)n * 256 + lane * 4) = o;
}

// ---------------- GEMM: out[M=50000, 256] (+)= sum_s A_s[M,256] @ W_s[256,256] ----------------
// A_s = xa + s*strideR (bf16, row-major [n][k]); W at wb + (wseg0+s)*65536, layout [n][k] (transposed).
// first: overwrite out; final: add bias + relu.

#define BM 128
#define BN 128
#define BK 64

__global__ __launch_bounds__(256) void k_gemm(const ushort* __restrict__ xa, long strideR,
                                              int nseg, const ushort* __restrict__ wb,
                                              int wseg0, const float* __restrict__ bias,
                                              float* __restrict__ out, int first, int final_) {
  __shared__ ushort As[BM][BK + 8];
  __shared__ ushort Bs[BN][BK + 8];
  int t = threadIdx.x;
  int lane = t & 63, wid = t >> 6;
  int wm = wid >> 1, wn = wid & 1;
  int i0 = blockIdx.x * BM, n0 = blockIdx.y * BN;

  f32x4 acc[4][4];
  #pragma unroll
  for (int a = 0; a < 4; ++a)
    #pragma unroll
    for (int b = 0; b < 4; ++b) acc[a][b] = (f32x4){0.f, 0.f, 0.f, 0.f};

  for (int s = 0; s < nseg; ++s) {
    const ushort* A = xa + (size_t)s * strideR;
    const ushort* W = wb + (size_t)(wseg0 + s) * 65536;
    for (int kt = 0; kt < 256; kt += BK) {
      __syncthreads();
      // stage A: 128 rows x 64 cols bf16 = 1024 x 16B chunks, 4 per thread
      #pragma unroll
      for (int it = 0; it < 4; ++it) {
        int flat = t + it * 256;
        int row = flat >> 3, seg = flat & 7;
        int gr = i0 + row;
        uint4 v = {0u, 0u, 0u, 0u};
        if (gr < NN) v = *(const uint4*)(A + (size_t)gr * 256 + kt + seg * 8);
        *(uint4*)(&As[row][seg * 8]) = v;
      }
      // stage B (n-major): 128 n-rows x 64 k
      #pragma unroll
      for (int it = 0; it < 4; ++it) {
        int flat = t + it * 256;
        int row = flat >> 3, seg = flat & 7;
        *(uint4*)(&Bs[row][seg * 8]) =
            *(const uint4*)(W + (size_t)(n0 + row) * 256 + kt + seg * 8);
      }
      __syncthreads();
      #pragma unroll
      for (int kk = 0; kk < 2; ++kk) {
        int ko = kk * 32 + (lane >> 4) * 8;
        short8v a_frag[4], b_frag[4];
        #pragma unroll
        for (int mi = 0; mi < 4; ++mi) {
          int row = wm * 64 + mi * 16 + (lane & 15);
          a_frag[mi] = *(const short8v*)(&As[row][ko]);
        }
        #pragma unroll
        for (int ni = 0; ni < 4; ++ni) {
          int col = wn * 64 + ni * 16 + (lane & 15);
          b_frag[ni] = *(const short8v*)(&Bs[col][ko]);
        }
        #pragma unroll
        for (int mi = 0; mi < 4; ++mi)
          #pragma unroll
          for (int ni = 0; ni < 4; ++ni)
            acc[mi][ni] = __builtin_amdgcn_mfma_f32_16x16x32_bf16(
                a_frag[mi], b_frag[ni], acc[mi][ni], 0, 0, 0);
      }
    }
  }

  // epilogue: C elem (col = lane&15, row = (lane>>4)*4 + reg)
  #pragma unroll
  for (int mi = 0; mi < 4; ++mi) {
    int rbase = i0 + wm * 64 + mi * 16 + ((lane >> 4) << 2);
    #pragma unroll
    for (int ni = 0; ni < 4; ++ni) {
      int col = n0 + wn * 64 + ni * 16 + (lane & 15);
      float bv = final_ ? bias[col] : 0.f;
      #pragma unroll
      for (int rg = 0; rg < 4; ++rg) {
        int gm = rbase + rg;
        if (gm < NN) {
          size_t o = (size_t)gm * 256 + col;
          float v = acc[mi][ni][rg];
          if (!first) v += out[o];
          if (final_) v = fmaxf(v + bv, 0.f);
          out[o] = v;
        }
      }
    }
  }
}

// ---------------- host ----------------

extern "C" void kernel_launch(void* const* d_in, const int* in_sizes, int n_in,
                              void* d_out, int out_size, void* d_ws, size_t ws_size,
                              hipStream_t stream) {
  const float* x = (const float*)d_in[0];
  const float* w = (const float*)d_in[1];
  const float* bias = (const float*)d_in[2];
  const float* lw = (const float*)d_in[3];
  const int* src = (const int*)d_in[4];
  const int* dst = (const int*)d_in[5];
  float* out = (float*)d_out;

  char* ws = (char*)d_ws;
  size_t off = 0;
  auto carve = [&](size_t bytes) {
    size_t o = off;
    off = (off + bytes + 255) & ~(size_t)255;
    return o;
  };
  int* deg = (int*)(ws + carve((size_t)NR * NN * 4));
  int* cur = (int*)(ws + carve((size_t)NR * NN * 4));
  int* offs = (int*)(ws + carve((size_t)NR * NN * 4));
  int* csr = (int*)(ws + carve((size_t)NR * NE * 4));
  ushort* wb = (ushort*)(ws + carve((size_t)9 * 65536 * 2));
  size_t base_bytes = off;
  size_t xa_full_bytes = (size_t)9 * NN * 256 * 2;
  ushort* xa = (ushort*)(ws + off);
  bool full = (ws_size >= base_bytes + xa_full_bytes);

  hipMemsetAsync(deg, 0, (size_t)NR * NN * 4 * 2, stream);  // deg + cur (contiguous)
  k_hist<<<4096, 256, 0, stream>>>(dst, deg);
  k_scan<<<NR, 1024, 0, stream>>>(deg, offs);
  k_fill<<<4096, 256, 0, stream>>>(src, dst, offs, cur, csr);
  k_wconv<<<(9 * 65536 + 255) / 256, 256, 0, stream>>>(w, lw, wb);

  dim3 gemm_grid((NN + BM - 1) / BM, 256 / BN);
  if (full) {
    long strideR = (long)NN * 256;
    k_agg<<<dim3((NN + 3) / 4, 9), 256, 0, stream>>>(x, csr, offs, deg, xa, strideR, 0);
    k_gemm<<<gemm_grid, 256, 0, stream>>>(xa, strideR, 9, wb, 0, bias, out, 1, 1);
  } else {
    for (int r = 0; r < 9; ++r) {
      k_agg<<<dim3((NN + 3) / 4, 1), 256, 0, stream>>>(x, csr, offs, deg, xa, 0, r);
      k_gemm<<<gemm_grid, 256, 0, stream>>>(xa, 0, 1, wb, r, bias, out,
                                            (r == 0) ? 1 : 0, (r == 8) ? 1 : 0);
    }
  }
  (void)in_sizes; (void)n_in; (void)out_size; (void)ws_size;
}

// Round 2
// 714.380 us; speedup vs baseline: 1.3987x; 1.3987x over previous
//
#include <hip/hip_runtime.h>
#include <hip/hip_bf16.h>

#define NN 50000
#define NPAD 50048   // pad so GEMM staging of the last M-block stays in-bounds
#define NR 8
#define NE 400000
#define DD 256

typedef __attribute__((ext_vector_type(8))) short short8v;
typedef __attribute__((ext_vector_type(4))) float f32x4;

static __device__ __forceinline__ ushort f2b(float f) {
  union { float f; unsigned u; } v; v.f = f;
  unsigned u = v.u;
  unsigned r = (u + 0x7fffu + ((u >> 16) & 1u)) >> 16;
  return (ushort)r;
}
static __device__ __forceinline__ float b2f(ushort u) {
  union { unsigned u; float f; } v; v.u = ((unsigned)u) << 16;
  return v.f;
}

// ---------------- CSR build ----------------

__global__ __launch_bounds__(256) void k_hist(const int* __restrict__ dst,
                                              int* __restrict__ deg) {
  int e = blockIdx.x * 256 + threadIdx.x;
  int r = blockIdx.y;
  if (e < NE) atomicAdd(&deg[r * NN + dst[(size_t)r * NE + e]], 1);
}

__global__ __launch_bounds__(1024) void k_scan(const int* __restrict__ deg,
                                               int* __restrict__ offs) {
  int r = blockIdx.x;
  int t = threadIdx.x, lane = t & 63, w = t >> 6;  // 16 waves
  __shared__ int wsum[16];
  __shared__ int carry;
  if (t == 0) carry = 0;
  __syncthreads();
  for (int base = 0; base < NN; base += 1024) {
    int v = (base + t < NN) ? deg[r * NN + base + t] : 0;
    int s = v;
    #pragma unroll
    for (int off = 1; off < 64; off <<= 1) {
      int u = __shfl_up(s, off, 64);
      if (lane >= off) s += u;
    }
    if (lane == 63) wsum[w] = s;
    __syncthreads();
    int wbase = 0, total = 0;
    #pragma unroll
    for (int i = 0; i < 16; ++i) {
      int ws_i = wsum[i];
      wbase += (i < w) ? ws_i : 0;
      total += ws_i;
    }
    int c = carry;
    if (base + t < NN) offs[r * NN + base + t] = c + wbase + (s - v);
    __syncthreads();
    if (t == 0) carry += total;
    __syncthreads();
  }
}

__global__ __launch_bounds__(256) void k_fill(const int* __restrict__ src,
                                              const int* __restrict__ dst,
                                              const int* __restrict__ offs,
                                              int* __restrict__ cur,
                                              int* __restrict__ csr) {
  int e = blockIdx.x * 256 + threadIdx.x;
  int r = blockIdx.y;
  if (e >= NE) return;
  int d = dst[(size_t)r * NE + e];
  int p = offs[r * NN + d] + atomicAdd(&cur[r * NN + d], 1);
  csr[(size_t)r * NE + p] = src[(size_t)r * NE + e];
}

// ---------------- x -> bf16 ----------------

__global__ __launch_bounds__(256) void k_xconv(const float* __restrict__ x,
                                               ushort* __restrict__ xb) {
  int i = blockIdx.x * 256 + threadIdx.x;  // one float4 per thread
  if (i >= NN * 64) return;
  float4 v = ((const float4*)x)[i];
  ushort4 o;
  o.x = f2b(v.x); o.y = f2b(v.y); o.z = f2b(v.z); o.w = f2b(v.w);
  ((ushort4*)xb)[i] = o;
}

// ---------------- weights -> bf16, transposed [seg][n][k] ----------------

__global__ __launch_bounds__(256) void k_wconv(const float* __restrict__ w,
                                               const float* __restrict__ lw,
                                               ushort* __restrict__ wb) {
  int i = blockIdx.x * 256 + threadIdx.x;
  if (i >= 9 * 65536) return;
  int s = i >> 16, rem = i & 65535, k = rem >> 8, n = rem & 255;
  float v = (s < 8) ? w[(size_t)s * 65536 + k * 256 + n] : lw[k * 256 + n];
  wb[(size_t)s * 65536 + (size_t)n * 256 + k] = f2b(v);
}

// ---------------- aggregation: one wave per (node, relation), bf16 gather ----------------

__global__ __launch_bounds__(256) void k_agg(const ushort* __restrict__ xb,
                                             const int* __restrict__ csr,
                                             const int* __restrict__ offs,
                                             const int* __restrict__ deg,
                                             ushort* __restrict__ xa,
                                             long strideR, int r0) {
  int wid = threadIdx.x >> 6, lane = threadIdx.x & 63;
  int n = blockIdx.x * 4 + wid;
  int r = r0 + blockIdx.y;
  if (n >= NN) return;
  int base = offs[r * NN + n];
  int dg = deg[r * NN + n];
  const int* lst = csr + (size_t)r * NE + base;
  float a0 = 0.f, a1 = 0.f, a2 = 0.f, a3 = 0.f;
  int j = 0;
  for (; j + 1 < dg; j += 2) {
    int s0 = lst[j], s1 = lst[j + 1];
    ushort4 v0 = *(const ushort4*)(xb + (size_t)s0 * 256 + lane * 4);
    ushort4 v1 = *(const ushort4*)(xb + (size_t)s1 * 256 + lane * 4);
    a0 += b2f(v0.x) + b2f(v1.x);
    a1 += b2f(v0.y) + b2f(v1.y);
    a2 += b2f(v0.z) + b2f(v1.z);
    a3 += b2f(v0.w) + b2f(v1.w);
  }
  if (j < dg) {
    int s0 = lst[j];
    ushort4 v0 = *(const ushort4*)(xb + (size_t)s0 * 256 + lane * 4);
    a0 += b2f(v0.x); a1 += b2f(v0.y); a2 += b2f(v0.z); a3 += b2f(v0.w);
  }
  float inv = 1.f / (float)max(dg, 1);
  ushort4 o;
  o.x = f2b(a0 * inv); o.y = f2b(a1 * inv); o.z = f2b(a2 * inv); o.w = f2b(a3 * inv);
  *(ushort4*)(xa + (size_t)(r - r0) * strideR + (size_t)n * 256 + lane * 4) = o;
}

// ---------------- GEMM (m97-style): out[M,256] (+)= sum_s A_s[M,256] @ W_s ----------------
// A_s = xa + s*strideR for seg<8 (global seg id wseg0+s), xb for seg 8.
// W layout [n][k] (pre-transposed bf16). Linear LDS + global_load_lds width 16.

#define BM 128
#define BN 128
#define BK 64

__global__ __launch_bounds__(256) void k_gemm(const ushort* __restrict__ xa, long strideR,
                                              int nseg, const ushort* __restrict__ xb8,
                                              const ushort* __restrict__ wb, int wseg0,
                                              const float* __restrict__ bias,
                                              float* __restrict__ out, int first, int final_) {
  __shared__ ushort As[BM * BK];
  __shared__ ushort Bs[BN * BK];
  int t = threadIdx.x;
  int lane = t & 63, wid = t >> 6;
  int wm = wid >> 1, wn = wid & 1;
  int i0 = blockIdx.x * BM, n0 = blockIdx.y * BN;

  f32x4 acc[4][4];
  #pragma unroll
  for (int a = 0; a < 4; ++a)
    #pragma unroll
    for (int b = 0; b < 4; ++b) acc[a][b] = (f32x4){0.f, 0.f, 0.f, 0.f};

  for (int s = 0; s < nseg; ++s) {
    const ushort* A = (wseg0 + s < 8) ? (xa + (size_t)s * strideR) : xb8;
    const ushort* W = wb + (size_t)(wseg0 + s) * 65536;
    for (int kt = 0; kt < 256; kt += BK) {
      __syncthreads();  // prior compute's ds_reads done before overwrite
      #pragma unroll
      for (int it = 0; it < 4; ++it) {
        int flat = it * 256 + t;
        int row = flat >> 3, seg = flat & 7;
        const ushort* ga = A + (size_t)(i0 + row) * 256 + kt + seg * 8;
        __builtin_amdgcn_global_load_lds(
            (const __attribute__((address_space(1))) unsigned int*)ga,
            (__attribute__((address_space(3))) unsigned int*)(As + flat * 8), 16, 0, 0);
      }
      #pragma unroll
      for (int it = 0; it < 4; ++it) {
        int flat = it * 256 + t;
        int row = flat >> 3, seg = flat & 7;
        const ushort* gb = W + (size_t)(n0 + row) * 256 + kt + seg * 8;
        __builtin_amdgcn_global_load_lds(
            (const __attribute__((address_space(1))) unsigned int*)gb,
            (__attribute__((address_space(3))) unsigned int*)(Bs + flat * 8), 16, 0, 0);
      }
      __syncthreads();  // drains vmcnt(0): LDS tiles ready
      #pragma unroll
      for (int kk = 0; kk < 2; ++kk) {
        int ko = kk * 32 + (lane >> 4) * 8;
        short8v a_frag[4], b_frag[4];
        #pragma unroll
        for (int mi = 0; mi < 4; ++mi)
          a_frag[mi] = *(const short8v*)(As + (wm * 64 + mi * 16 + (lane & 15)) * BK + ko);
        #pragma unroll
        for (int ni = 0; ni < 4; ++ni)
          b_frag[ni] = *(const short8v*)(Bs + (wn * 64 + ni * 16 + (lane & 15)) * BK + ko);
        #pragma unroll
        for (int mi = 0; mi < 4; ++mi)
          #pragma unroll
          for (int ni = 0; ni < 4; ++ni)
            acc[mi][ni] = __builtin_amdgcn_mfma_f32_16x16x32_bf16(
                a_frag[mi], b_frag[ni], acc[mi][ni], 0, 0, 0);
      }
    }
  }

  // epilogue: C elem (col = lane&15, row = (lane>>4)*4 + reg)
  #pragma unroll
  for (int mi = 0; mi < 4; ++mi) {
    int rbase = i0 + wm * 64 + mi * 16 + ((lane >> 4) << 2);
    #pragma unroll
    for (int ni = 0; ni < 4; ++ni) {
      int col = n0 + wn * 64 + ni * 16 + (lane & 15);
      float bv = final_ ? bias[col] : 0.f;
      #pragma unroll
      for (int rg = 0; rg < 4; ++rg) {
        int gm = rbase + rg;
        if (gm < NN) {
          size_t o = (size_t)gm * 256 + col;
          float v = acc[mi][ni][rg];
          if (!first) v += out[o];
          if (final_) v = fmaxf(v + bv, 0.f);
          out[o] = v;
        }
      }
    }
  }
}

// ---------------- host ----------------

extern "C" void kernel_launch(void* const* d_in, const int* in_sizes, int n_in,
                              void* d_out, int out_size, void* d_ws, size_t ws_size,
                              hipStream_t stream) {
  const float* x = (const float*)d_in[0];
  const float* w = (const float*)d_in[1];
  const float* bias = (const float*)d_in[2];
  const float* lw = (const float*)d_in[3];
  const int* src = (const int*)d_in[4];
  const int* dst = (const int*)d_in[5];
  float* out = (float*)d_out;

  char* ws = (char*)d_ws;
  size_t off = 0;
  auto carve = [&](size_t bytes) {
    size_t o = off;
    off = (off + bytes + 255) & ~(size_t)255;
    return o;
  };
  int* deg = (int*)(ws + carve((size_t)NR * NN * 4));
  int* offs = (int*)(ws + carve((size_t)NR * NN * 4));
  int* csr = (int*)(ws + carve((size_t)NR * NE * 4));
  ushort* wb = (ushort*)(ws + carve((size_t)9 * 65536 * 2));
  ushort* xb = (ushort*)(ws + carve((size_t)NPAD * 256 * 2));
  size_t base_bytes = off;
  size_t xa_full_bytes = (size_t)NR * NPAD * 256 * 2;
  ushort* xa = (ushort*)(ws + off);
  // cur[] overlays xa region: cur is dead after k_fill, xa written after.
  int* cur = (int*)(ws + off);
  bool full = (ws_size >= base_bytes + xa_full_bytes);

  hipMemsetAsync(deg, 0, (size_t)NR * NN * 4, stream);
  hipMemsetAsync(cur, 0, (size_t)NR * NN * 4, stream);
  dim3 egrid((NE + 255) / 256, NR);
  k_hist<<<egrid, 256, 0, stream>>>(dst, deg);
  k_scan<<<NR, 1024, 0, stream>>>(deg, offs);
  k_fill<<<egrid, 256, 0, stream>>>(src, dst, offs, cur, csr);
  k_xconv<<<(NN * 64 + 255) / 256, 256, 0, stream>>>(x, xb);
  k_wconv<<<(9 * 65536 + 255) / 256, 256, 0, stream>>>(w, lw, wb);

  dim3 gemm_grid((NN + BM - 1) / BM, 256 / BN);
  if (full) {
    long strideR = (long)NPAD * 256;
    k_agg<<<dim3((NN + 3) / 4, NR), 256, 0, stream>>>(xb, csr, offs, deg, xa, strideR, 0);
    k_gemm<<<gemm_grid, 256, 0, stream>>>(xa, strideR, 9, xb, wb, 0, bias, out, 1, 1);
  } else {
    // fallback: one relation at a time reusing a single xa segment
    for (int r = 0; r < 8; ++r) {
      k_agg<<<dim3((NN + 3) / 4, 1), 256, 0, stream>>>(xb, csr, offs, deg, xa, 0, r);
      k_gemm<<<gemm_grid, 256, 0, stream>>>(xa, 0, 1, xb, wb, r, bias, out,
                                            (r == 0) ? 1 : 0, 0);
    }
    k_gemm<<<gemm_grid, 256, 0, stream>>>(xa, 0, 1, xb, wb, 8, bias, out, 0, 1);
  }
  (void)in_sizes; (void)n_in; (void)out_size;
}